// Round 2
// baseline (197.371 us; speedup 1.0000x reference)
//
#include <hip/hip_runtime.h>
#include <hip/hip_bf16.h>
#include <stdint.h>

typedef __attribute__((ext_vector_type(8))) __bf16 bf16x8;
typedef __attribute__((ext_vector_type(4))) float f32x4;

#define B_  2
#define H_  16
#define S_  2048
#define D_  128
#define BH_ (B_*H_)
#define NQT (S_/64)   // 32 q-tiles of 64 rows

__device__ __forceinline__ uint32_t f2bf1(float f){
  uint32_t u = __builtin_bit_cast(uint32_t, f);
  return (u + 0x7fffu + ((u >> 16) & 1u)) >> 16;   // RNE fp32 -> bf16
}
__device__ __forceinline__ uint32_t pk2(float a, float b){
  return f2bf1(a) | (f2bf1(b) << 16);
}

// ---------- pre-pass 1: K fp32 -> bf16, layout unchanged [bh][kv][d] ----------
__global__ void k_cvt(const float* __restrict__ in, unsigned short* __restrict__ out, int n4){
  int i = blockIdx.x * blockDim.x + threadIdx.x;
  int stride = gridDim.x * blockDim.x;
  for (; i < n4; i += stride){
    float4 f = ((const float4*)in)[i];
    ushort4 o;
    o.x = (unsigned short)f2bf1(f.x);
    o.y = (unsigned short)f2bf1(f.y);
    o.z = (unsigned short)f2bf1(f.z);
    o.w = (unsigned short)f2bf1(f.w);
    ((ushort4*)out)[i] = o;
  }
}

// ---------- pre-pass 2: V fp32 [bh][kv][d] -> Vt bf16 [bh][d][kv] ----------
__global__ void v_trans(const float* __restrict__ V, unsigned short* __restrict__ Vt){
  __shared__ __attribute__((aligned(16))) unsigned short t[64*68];
  const int kv0 = blockIdx.x * 64, d0 = blockIdx.y * 64, bh = blockIdx.z;
  const int tid = threadIdx.x;
  const float* Vp = V + (size_t)bh * S_ * D_;
  for (int i = 0; i < 4; i++){
    int f = tid + i*256;
    int kv = f >> 4, c4 = f & 15;
    float4 v = *(const float4*)(Vp + (size_t)(kv0+kv)*D_ + d0 + c4*4);
    *(uint2*)&t[kv*68 + c4*4] = make_uint2(pk2(v.x,v.y), pk2(v.z,v.w));
  }
  __syncthreads();
  unsigned short* Vo = Vt + (size_t)bh * D_ * S_;
  for (int i = 0; i < 4; i++){
    int g = tid + i*256;
    int d = g >> 4, c = g & 15, kv = c*4;
    ushort4 o;
    o.x = t[(kv+0)*68 + d];
    o.y = t[(kv+1)*68 + d];
    o.z = t[(kv+2)*68 + d];
    o.w = t[(kv+3)*68 + d];
    *(ushort4*)(Vo + (size_t)(d0+d)*S_ + kv0 + kv) = o;
  }
}

// ---------- main flash-attention kernel ----------
// 4 waves x 16 q-rows = QBLK 64; KVBLK 64; causal; double-buffered K/V with
// async reg-staged prefetch; causal balance via q-tile pairing (31-j, j).
__global__ __launch_bounds__(256, 2)
void attn_fwd(const float* __restrict__ Q, const unsigned short* __restrict__ Kb,
              const unsigned short* __restrict__ Vt, float* __restrict__ Out){
  __shared__ __attribute__((aligned(16))) unsigned short Klds[2][64*128]; // [kv][d] swz ^((kv&7)<<4)
  __shared__ __attribute__((aligned(16))) unsigned short Vlds[2][128*64]; // [d][kv] swz ^((d&7)<<4)
  __shared__ __attribute__((aligned(16))) unsigned short Plds[4][16*64];  // per-wave [q][kv] swz

  const int bh   = blockIdx.y;
  const int tid  = threadIdx.x;
  const int wave = tid >> 6, lane = tid & 63;
  const int ql   = lane & 15, hi = lane >> 4;
  const float qs = 0.08838834764831845f * 1.44269504088896f; // (1/sqrt(128))*log2(e)

  const unsigned short* Kg = Kb + (size_t)bh * S_ * D_;
  const unsigned short* Vg = Vt + (size_t)bh * D_ * S_;

  // per-thread staging geometry (constant across tiles)
  int kfi[4], vfi[4];          // flat chunk ids
  int kwb[4], vwb[4];          // swizzled LDS write byte offsets
  #pragma unroll
  for (int i = 0; i < 4; i++){
    int f = tid + i*256;
    kfi[i] = f;
    kwb[i] = ((f >> 4)*256 + (f & 15)*16) ^ (((f >> 4) & 7) << 4);
    vfi[i] = f;
    vwb[i] = ((f >> 3)*128 + (f & 7)*16) ^ (((f >> 3) & 7) << 4);
  }

  for (int pass = 0; pass < 2; ++pass){
    const int qt  = pass ? (int)blockIdx.x : (NQT - 1 - (int)blockIdx.x);
    const int nt  = qt + 1;
    const int wq0 = qt*64 + wave*16;

    // --- Q fragments (B-operand of swapped QK^T)
    uint4 qf[4];
    {
      const float* Qp = Q + ((size_t)bh * S_ + (wq0 + ql)) * D_;
      #pragma unroll
      for (int ks = 0; ks < 4; ks++){
        float4 a = *(const float4*)(Qp + ks*32 + hi*8);
        float4 b = *(const float4*)(Qp + ks*32 + hi*8 + 4);
        qf[ks] = make_uint4(pk2(a.x,a.y), pk2(a.z,a.w), pk2(b.x,b.y), pk2(b.z,b.w));
      }
    }

    f32x4 o[8];
    #pragma unroll
    for (int nb = 0; nb < 8; nb++) o[nb] = (f32x4)(0.f);
    float m_run = -INFINITY, l_run = 0.f;

    // staging pointers for next tile to load (start at tile 0)
    const uint4* kp[4]; const uint4* vp[4];
    #pragma unroll
    for (int i = 0; i < 4; i++){
      kp[i] = (const uint4*)(Kg + (size_t)(kfi[i] >> 4)*D_ + (kfi[i] & 15)*8);
      vp[i] = (const uint4*)(Vg + (size_t)(vfi[i] >> 3)*S_ + (vfi[i] & 7)*8);
    }

    uint4 kr[4], vr[4];
    // --- prologue: stage tile 0 into buf 0
    #pragma unroll
    for (int i = 0; i < 4; i++){ kr[i] = *kp[i]; vr[i] = *vp[i]; kp[i] += 64*D_/8; vp[i] += 64/8; }
    {
      char* kb = (char*)&Klds[0][0];
      char* vb = (char*)&Vlds[0][0];
      #pragma unroll
      for (int i = 0; i < 4; i++){ *(uint4*)(kb + kwb[i]) = kr[i]; *(uint4*)(vb + vwb[i]) = vr[i]; }
    }
    __syncthreads();

    int cur = 0;
    for (int t = 0; t < nt; ++t){
      const bool pf = (t + 1 < nt);
      if (pf){
        #pragma unroll
        for (int i = 0; i < 4; i++){ kr[i] = *kp[i]; vr[i] = *vp[i]; kp[i] += 64*D_/8; vp[i] += 64/8; }
      }
      const int k0 = t*64;
      const char* Kc = (const char*)&Klds[cur][0];
      const char* Vc = (const char*)&Vlds[cur][0];

      // ---- swapped QK^T: sa[mb][r] = S^T[kv = mb*16+hi*4+r][q = ql]
      f32x4 sa[4];
      __builtin_amdgcn_s_setprio(1);
      #pragma unroll
      for (int mb = 0; mb < 4; mb++){
        sa[mb] = (f32x4)(0.f);
        const int row = ql + mb*16;
        #pragma unroll
        for (int ks = 0; ks < 4; ks++){
          int byte = (row*256 + ks*64 + hi*16) ^ ((row & 7) << 4);
          bf16x8 kf = *(const bf16x8*)(Kc + byte);
          sa[mb] = __builtin_amdgcn_mfma_f32_16x16x32_bf16(
                      kf, __builtin_bit_cast(bf16x8, qf[ks]), sa[mb], 0, 0, 0);
        }
      }
      __builtin_amdgcn_s_setprio(0);

      // ---- online softmax, log2 domain, wave-parallel
      float p[16];
      float pm = -INFINITY;
      const bool diag = (t == nt - 1);
      const int q_abs = wq0 + ql;
      #pragma unroll
      for (int mb = 0; mb < 4; mb++){
        #pragma unroll
        for (int r = 0; r < 4; r++){
          float s = sa[mb][r] * qs;
          int kv = k0 + mb*16 + hi*4 + r;
          if (diag && kv > q_abs) s = -1e30f;
          p[mb*4 + r] = s;
          pm = fmaxf(pm, s);
        }
      }
      pm = fmaxf(pm, __shfl_xor(pm, 16));
      pm = fmaxf(pm, __shfl_xor(pm, 32));
      // defer-max: only rescale when the running max grew by > 11.5 (log2) ~ e^8
      if (__any(pm > m_run + 11.5f)){
        float m_new = fmaxf(m_run, pm);
        float fac = exp2f(m_run - m_new);      // 0 when m_run == -inf
        float fv[4];
        #pragma unroll
        for (int r = 0; r < 4; r++) fv[r] = __shfl(fac, hi*4 + r);
        #pragma unroll
        for (int nb = 0; nb < 8; nb++){
          o[nb][0] *= fv[0]; o[nb][1] *= fv[1]; o[nb][2] *= fv[2]; o[nb][3] *= fv[3];
        }
        l_run *= fac;
        m_run = m_new;
      }
      float rs = 0.f;
      #pragma unroll
      for (int i = 0; i < 16; i++){ p[i] = exp2f(p[i] - m_run); rs += p[i]; }
      rs += __shfl_xor(rs, 16);
      rs += __shfl_xor(rs, 32);
      l_run += rs;

      // ---- P -> per-wave LDS (bf16), packed b64 writes
      #pragma unroll
      for (int mb = 0; mb < 4; mb++){
        uint32_t lo  = pk2(p[mb*4+0], p[mb*4+1]);
        uint32_t hi2 = pk2(p[mb*4+2], p[mb*4+3]);
        int byte = (ql*128 + mb*32 + hi*8) ^ ((ql & 7) << 4);
        *(uint2*)((char*)&Plds[wave][0] + byte) = make_uint2(lo, hi2);
      }

      // ---- PV: O[q][d] += P[q][kv] * V[kv][d]
      __builtin_amdgcn_s_setprio(1);
      #pragma unroll
      for (int ks = 0; ks < 2; ks++){
        int pb = (ql*128 + ks*64 + hi*16) ^ ((ql & 7) << 4);
        bf16x8 pfr = *(const bf16x8*)((const char*)&Plds[wave][0] + pb);
        #pragma unroll
        for (int nb = 0; nb < 8; nb++){
          int d = ql + nb*16;
          int vb = (d*128 + ks*64 + hi*16) ^ ((d & 7) << 4);
          bf16x8 vf = *(const bf16x8*)(Vc + vb);
          o[nb] = __builtin_amdgcn_mfma_f32_16x16x32_bf16(pfr, vf, o[nb], 0, 0, 0);
        }
      }
      __builtin_amdgcn_s_setprio(0);

      __syncthreads();                    // everyone done reading buf[cur]
      if (pf){
        const int nxt = cur ^ 1;
        char* kb = (char*)&Klds[nxt][0];
        char* vb = (char*)&Vlds[nxt][0];
        #pragma unroll
        for (int i = 0; i < 4; i++){ *(uint4*)(kb + kwb[i]) = kr[i]; *(uint4*)(vb + vwb[i]) = vr[i]; }
        __syncthreads();                  // buf[nxt] ready
        cur = nxt;
      }
    }

    // ---- epilogue: divide by l (shfl broadcast per-row), write fp32 output
    float rl[4];
    #pragma unroll
    for (int r = 0; r < 4; r++) rl[r] = 1.f / __shfl(l_run, hi*4 + r);

    float* Op = Out + ((size_t)bh * S_ + wq0) * D_;
    #pragma unroll
    for (int nb = 0; nb < 8; nb++){
      #pragma unroll
      for (int r = 0; r < 4; r++){
        Op[(size_t)(hi*4 + r)*D_ + nb*16 + ql] = o[nb][r] * rl[r];
      }
    }
  }
}

extern "C" void kernel_launch(void* const* d_in, const int* in_sizes, int n_in,
                              void* d_out, int out_size, void* d_ws, size_t ws_size,
                              hipStream_t stream){
  const float* Q = (const float*)d_in[0];
  const float* K = (const float*)d_in[1];
  const float* V = (const float*)d_in[2];
  float* Out = (float*)d_out;

  unsigned short* Kb = (unsigned short*)d_ws;
  unsigned short* Vt = Kb + (size_t)BH_ * S_ * D_;

  k_cvt<<<2048, 256, 0, stream>>>(K, Kb, BH_*S_*D_/4);
  v_trans<<<dim3(S_/64, D_/64, BH_), 256, 0, stream>>>(V, Vt);
  attn_fwd<<<dim3(NQT/2, BH_), 256, 0, stream>>>(Q, Kb, Vt, Out);
}

// Round 3
// 115.605 us; speedup vs baseline: 1.7073x; 1.7073x over previous
//
#include <hip/hip_runtime.h>
#include <hip/hip_bf16.h>
#include <stdint.h>

typedef __attribute__((ext_vector_type(8))) __bf16 bf16x8;
typedef __attribute__((ext_vector_type(4))) float f32x4;

#define B_  2
#define H_  16
#define S_  2048
#define D_  128
#define BH_ (B_*H_)
#define NQB 16    // q-blocks of 128 rows

__device__ __forceinline__ uint32_t f2bf1(float f){
  uint32_t u = __builtin_bit_cast(uint32_t, f);
  return (u + 0x7fffu + ((u >> 16) & 1u)) >> 16;   // RNE fp32 -> bf16
}
__device__ __forceinline__ uint32_t pk2(float a, float b){
  return f2bf1(a) | (f2bf1(b) << 16);
}

// async global->LDS, 16B/lane, linear LDS dest (base + lane*16)
__device__ __forceinline__ void gld16(const void* g, void* l){
  __builtin_amdgcn_global_load_lds(
      (const __attribute__((address_space(1))) void*)g,
      (__attribute__((address_space(3))) void*)(uintptr_t)l, 16, 0, 0);
}

// ---------- pre-pass 1: K fp32 -> bf16 [bh][kv][d] ----------
__global__ void k_cvt(const float* __restrict__ in, unsigned short* __restrict__ out, int n4){
  int i = blockIdx.x * blockDim.x + threadIdx.x;
  int stride = gridDim.x * blockDim.x;
  for (; i < n4; i += stride){
    float4 f = ((const float4*)in)[i];
    ushort4 o;
    o.x = (unsigned short)f2bf1(f.x);
    o.y = (unsigned short)f2bf1(f.y);
    o.z = (unsigned short)f2bf1(f.z);
    o.w = (unsigned short)f2bf1(f.w);
    ((ushort4*)out)[i] = o;
  }
}

// ---------- pre-pass 2: V fp32 [bh][kv][d] -> Vt bf16 [bh][d][kv] ----------
__global__ void v_trans(const float* __restrict__ V, unsigned short* __restrict__ Vt){
  __shared__ __attribute__((aligned(16))) unsigned short t[64*68];
  const int kv0 = blockIdx.x * 64, d0 = blockIdx.y * 64, bh = blockIdx.z;
  const int tid = threadIdx.x;
  const float* Vp = V + (size_t)bh * S_ * D_;
  for (int i = 0; i < 4; i++){
    int f = tid + i*256;
    int kv = f >> 4, c4 = f & 15;
    float4 v = *(const float4*)(Vp + (size_t)(kv0+kv)*D_ + d0 + c4*4);
    *(uint2*)&t[kv*68 + c4*4] = make_uint2(pk2(v.x,v.y), pk2(v.z,v.w));
  }
  __syncthreads();
  unsigned short* Vo = Vt + (size_t)bh * D_ * S_;
  for (int i = 0; i < 4; i++){
    int g = tid + i*256;
    int d = g >> 4, c = g & 15, kv = c*4;
    ushort4 o;
    o.x = t[(kv+0)*68 + d];
    o.y = t[(kv+1)*68 + d];
    o.z = t[(kv+2)*68 + d];
    o.w = t[(kv+3)*68 + d];
    *(ushort4*)(Vo + (size_t)(d0+d)*S_ + kv0 + kv) = o;
  }
}

// ---------- main flash-attention kernel ----------
// 4 waves x 32 q-rows (2x 16-row subtiles) = 128 q/block; KVBLK=64.
// K/V double-buffered via global_load_lds (pre-swizzled source, linear dest),
// 1 barrier/iter. K and V fragments reused across both subtiles.
__global__ __launch_bounds__(256, 2)
void attn_fwd(const float* __restrict__ Q, const unsigned short* __restrict__ Kb,
              const unsigned short* __restrict__ Vt, float* __restrict__ Out){
  __shared__ __attribute__((aligned(16))) unsigned short Klds[2][64*128];   // [kv][d] swz ^((kv&7)<<4)
  __shared__ __attribute__((aligned(16))) unsigned short Vlds[2][128*64];   // [d][kv] swz ^((d&7)<<4)
  __shared__ __attribute__((aligned(16))) unsigned short Plds[4][2][16*64]; // per-wave/sub [q][kv] swz

  // block mapping: xcd = bi&7 gets 4 bh's; heavy q-blocks first (bi<256),
  // complement (bi, bi+256) share bh and sum to constant work.
  const int bi   = blockIdx.x;
  const int bh   = (bi & 7) + 8*((bi >> 3) & 3);
  const int rest = bi >> 5;                 // 0..15
  const int j    = rest & 7;
  const int qb   = (rest < 8) ? (15 - j) : j;

  const int tid  = threadIdx.x;
  const int wave = tid >> 6, lane = tid & 63;
  const int ql   = lane & 15, hi = lane >> 4;
  const int wq0  = qb*128 + wave*32;
  const int dt   = wq0 >> 6;                // wave's diagonal kv-tile
  const int nt   = 2*qb + 2;
  const float qs = 0.08838834764831845f * 1.44269504088896f; // (1/sqrt(128))*log2(e)

  const char* Kg = (const char*)(Kb + (size_t)bh * S_ * D_);
  const char* Vg = (const char*)(Vt + (size_t)bh * D_ * S_);

  // staging source offsets: linear LDS dest byte p = wave*4096 + i*1024 + lane*16
  // K: row r = p>>8, src col = (p&255) ^ ((r&7)<<4)
  // V: row d = p>>7, src col = (p&127) ^ ((d&7)<<4)
  uint32_t koff[4], voff[4];
  #pragma unroll
  for (int i = 0; i < 4; i++){
    int kr = wave*16 + i*4 + (lane >> 4);
    koff[i] = kr*256 + (((lane & 15) ^ ((i & 1)*4 + (lane >> 4))) << 4);
    int vr = wave*32 + i*8 + (lane >> 3);
    voff[i] = vr*(S_*2) + (((lane & 7) ^ (lane >> 3)) << 4);
  }

  auto stage = [&](int nxt, int t){
    const char* kp = Kg + t*16384;          // t*64 rows * 256 B
    const char* vp = Vg + t*128;            // t*64 kv * 2 B
    char* kd = (char*)&Klds[nxt][0] + wave*4096;
    char* vd = (char*)&Vlds[nxt][0] + wave*4096;
    #pragma unroll
    for (int i = 0; i < 4; i++){
      gld16(kp + koff[i], kd + i*1024);
      gld16(vp + voff[i], vd + i*1024);
    }
  };

  // Q fragments (B-operand of swapped QK^T), 2 subtiles
  uint4 qf[2][4];
  #pragma unroll
  for (int sub = 0; sub < 2; sub++){
    const float* Qp = Q + ((size_t)bh * S_ + (wq0 + sub*16 + ql)) * D_;
    #pragma unroll
    for (int ks = 0; ks < 4; ks++){
      float4 a = *(const float4*)(Qp + ks*32 + hi*8);
      float4 b = *(const float4*)(Qp + ks*32 + hi*8 + 4);
      qf[sub][ks] = make_uint4(pk2(a.x,a.y), pk2(a.z,a.w), pk2(b.x,b.y), pk2(b.z,b.w));
    }
  }

  f32x4 o[2][8];
  #pragma unroll
  for (int sub = 0; sub < 2; sub++)
    #pragma unroll
    for (int nb = 0; nb < 8; nb++) o[sub][nb] = (f32x4)(0.f);
  float m_run[2] = {-INFINITY, -INFINITY};
  float l_run[2] = {0.f, 0.f};

  stage(0, 0);
  __syncthreads();

  int cur = 0;
  for (int t = 0; t < nt; ++t){
    if (t + 1 < nt) stage(cur ^ 1, t + 1);  // async prefetch, drains at barrier

    if (t <= dt){
      const int k0 = t*64;
      const bool diag = (t == dt);
      const char* Kc = (const char*)&Klds[cur][0];
      const char* Vc = (const char*)&Vlds[cur][0];

      // ---- swapped QK^T: K fragment read once, used for both subtiles
      f32x4 sa[2][4];
      __builtin_amdgcn_s_setprio(1);
      #pragma unroll
      for (int mb = 0; mb < 4; mb++){
        sa[0][mb] = (f32x4)(0.f);
        sa[1][mb] = (f32x4)(0.f);
        const int row = ql + mb*16;
        #pragma unroll
        for (int ks = 0; ks < 4; ks++){
          int byte = (row*256 + ks*64 + hi*16) ^ ((row & 7) << 4);
          bf16x8 kf = *(const bf16x8*)(Kc + byte);
          sa[0][mb] = __builtin_amdgcn_mfma_f32_16x16x32_bf16(
                        kf, __builtin_bit_cast(bf16x8, qf[0][ks]), sa[0][mb], 0, 0, 0);
          sa[1][mb] = __builtin_amdgcn_mfma_f32_16x16x32_bf16(
                        kf, __builtin_bit_cast(bf16x8, qf[1][ks]), sa[1][mb], 0, 0, 0);
        }
      }
      __builtin_amdgcn_s_setprio(0);

      // ---- online softmax (log2 domain, defer-max), per subtile
      #pragma unroll
      for (int sub = 0; sub < 2; sub++){
        float p[16];
        float pm = -INFINITY;
        const int q_abs = wq0 + sub*16 + ql;
        #pragma unroll
        for (int mb = 0; mb < 4; mb++){
          #pragma unroll
          for (int r = 0; r < 4; r++){
            float s = sa[sub][mb][r] * qs;
            int kv = k0 + mb*16 + hi*4 + r;
            if (diag && kv > q_abs) s = -1e30f;
            p[mb*4 + r] = s;
            pm = fmaxf(pm, s);
          }
        }
        pm = fmaxf(pm, __shfl_xor(pm, 16));
        pm = fmaxf(pm, __shfl_xor(pm, 32));
        if (__any(pm > m_run[sub] + 11.5f)){
          float mn  = fmaxf(m_run[sub], pm);
          float fac = exp2f(m_run[sub] - mn);
          float f0 = __shfl(fac, hi*4 + 0), f1 = __shfl(fac, hi*4 + 1);
          float f2 = __shfl(fac, hi*4 + 2), f3 = __shfl(fac, hi*4 + 3);
          #pragma unroll
          for (int nb = 0; nb < 8; nb++){
            o[sub][nb][0] *= f0; o[sub][nb][1] *= f1;
            o[sub][nb][2] *= f2; o[sub][nb][3] *= f3;
          }
          l_run[sub] *= fac;
          m_run[sub] = mn;
        }
        float rs = 0.f;
        #pragma unroll
        for (int q2 = 0; q2 < 16; q2++){ p[q2] = exp2f(p[q2] - m_run[sub]); rs += p[q2]; }
        rs += __shfl_xor(rs, 16);
        rs += __shfl_xor(rs, 32);
        l_run[sub] += rs;

        #pragma unroll
        for (int mb = 0; mb < 4; mb++){
          uint32_t lo = pk2(p[mb*4+0], p[mb*4+1]);
          uint32_t h2 = pk2(p[mb*4+2], p[mb*4+3]);
          int byte = (ql*128 + mb*32 + hi*8) ^ ((ql & 7) << 4);
          *(uint2*)((char*)&Plds[wave][sub][0] + byte) = make_uint2(lo, h2);
        }
      }

      // ---- PV: V fragment read once, used for both subtiles
      __builtin_amdgcn_s_setprio(1);
      #pragma unroll
      for (int ks = 0; ks < 2; ks++){
        int pb = (ql*128 + ks*64 + hi*16) ^ ((ql & 7) << 4);
        bf16x8 pfA = *(const bf16x8*)((const char*)&Plds[wave][0][0] + pb);
        bf16x8 pfB = *(const bf16x8*)((const char*)&Plds[wave][1][0] + pb);
        #pragma unroll
        for (int nb = 0; nb < 8; nb++){
          int d = ql + nb*16;
          int vb = (d*128 + ks*64 + hi*16) ^ ((d & 7) << 4);
          bf16x8 vf = *(const bf16x8*)(Vc + vb);
          o[0][nb] = __builtin_amdgcn_mfma_f32_16x16x32_bf16(pfA, vf, o[0][nb], 0, 0, 0);
          o[1][nb] = __builtin_amdgcn_mfma_f32_16x16x32_bf16(pfB, vf, o[1][nb], 0, 0, 0);
        }
      }
      __builtin_amdgcn_s_setprio(0);
    }

    __syncthreads();   // drains gld16 vmem + publishes buf[cur^1]
    cur ^= 1;
  }

  // ---- epilogue
  #pragma unroll
  for (int sub = 0; sub < 2; sub++){
    float r0 = 1.f / __shfl(l_run[sub], hi*4 + 0);
    float r1 = 1.f / __shfl(l_run[sub], hi*4 + 1);
    float r2 = 1.f / __shfl(l_run[sub], hi*4 + 2);
    float r3 = 1.f / __shfl(l_run[sub], hi*4 + 3);
    float* Op = Out + ((size_t)bh * S_ + wq0 + sub*16) * D_;
    #pragma unroll
    for (int nb = 0; nb < 8; nb++){
      Op[(size_t)(hi*4 + 0)*D_ + nb*16 + ql] = o[sub][nb][0] * r0;
      Op[(size_t)(hi*4 + 1)*D_ + nb*16 + ql] = o[sub][nb][1] * r1;
      Op[(size_t)(hi*4 + 2)*D_ + nb*16 + ql] = o[sub][nb][2] * r2;
      Op[(size_t)(hi*4 + 3)*D_ + nb*16 + ql] = o[sub][nb][3] * r3;
    }
  }
}

extern "C" void kernel_launch(void* const* d_in, const int* in_sizes, int n_in,
                              void* d_out, int out_size, void* d_ws, size_t ws_size,
                              hipStream_t stream){
  const float* Q = (const float*)d_in[0];
  const float* K = (const float*)d_in[1];
  const float* V = (const float*)d_in[2];
  float* Out = (float*)d_out;

  unsigned short* Kb = (unsigned short*)d_ws;
  unsigned short* Vt = Kb + (size_t)BH_ * S_ * D_;

  k_cvt<<<2048, 256, 0, stream>>>(K, Kb, BH_*S_*D_/4);
  v_trans<<<dim3(S_/64, D_/64, BH_), 256, 0, stream>>>(V, Vt);
  attn_fwd<<<NQB*BH_, 256, 0, stream>>>(Q, Kb, Vt, Out);
}

// Round 4
// 115.542 us; speedup vs baseline: 1.7082x; 1.0005x over previous
//
#include <hip/hip_runtime.h>
#include <hip/hip_bf16.h>
#include <stdint.h>

typedef __attribute__((ext_vector_type(8))) __bf16 bf16x8;
typedef __attribute__((ext_vector_type(4))) __bf16 bf16x4;
typedef __attribute__((ext_vector_type(4))) float f32x4;

#define B_  2
#define H_  16
#define S_  2048
#define D_  128
#define BH_ (B_*H_)

__device__ __forceinline__ uint32_t f2bf1(float f){
  uint32_t u = __builtin_bit_cast(uint32_t, f);
  return (u + 0x7fffu + ((u >> 16) & 1u)) >> 16;
}
__device__ __forceinline__ uint32_t pk2(float a, float b){
  return f2bf1(a) | (f2bf1(b) << 16);
}

// async global->LDS, 16B/lane, linear LDS dest
__device__ __forceinline__ void gld16(const void* g, void* l){
  __builtin_amdgcn_global_load_lds(
      (const __attribute__((address_space(1))) void*)g,
      (__attribute__((address_space(3))) void*)(uintptr_t)l, 16, 0, 0);
}

// unit table for split mode: code = qb*4 + mode (0=full,1=chunkA,2=chunkB), heavy-first
__device__ const unsigned char SPLIT_TAB[24] = {
  15*4+1,15*4+2, 7*4+0, 14*4+1,14*4+2, 13*4+1,13*4+2, 6*4+0,
  12*4+1,12*4+2, 11*4+1,11*4+2, 5*4+0, 10*4+1,10*4+2, 9*4+1,9*4+2,
  4*4+0, 8*4+1,8*4+2, 3*4+0, 2*4+0, 1*4+0, 0*4+0
};

// ---------- pre-pass 1: K fp32 -> bf16 [bh][kv][d] ----------
__global__ void k_cvt(const float* __restrict__ in, unsigned short* __restrict__ out, int n4){
  int i = blockIdx.x * blockDim.x + threadIdx.x;
  int stride = gridDim.x * blockDim.x;
  for (; i < n4; i += stride){
    float4 f = ((const float4*)in)[i];
    ushort4 o;
    o.x = (unsigned short)f2bf1(f.x);
    o.y = (unsigned short)f2bf1(f.y);
    o.z = (unsigned short)f2bf1(f.z);
    o.w = (unsigned short)f2bf1(f.w);
    ((ushort4*)out)[i] = o;
  }
}

// ---------- pre-pass 2: V fp32 [bh][kv][d] -> Vt bf16 [bh][d][kv] ----------
__global__ void v_trans(const float* __restrict__ V, unsigned short* __restrict__ Vt){
  __shared__ __attribute__((aligned(16))) unsigned short t[64*68];
  const int kv0 = blockIdx.x * 64, d0 = blockIdx.y * 64, bh = blockIdx.z;
  const int tid = threadIdx.x;
  const float* Vp = V + (size_t)bh * S_ * D_;
  for (int i = 0; i < 4; i++){
    int f = tid + i*256;
    int kv = f >> 4, c4 = f & 15;
    float4 v = *(const float4*)(Vp + (size_t)(kv0+kv)*D_ + d0 + c4*4);
    *(uint2*)&t[kv*68 + c4*4] = make_uint2(pk2(v.x,v.y), pk2(v.z,v.w));
  }
  __syncthreads();
  unsigned short* Vo = Vt + (size_t)bh * D_ * S_;
  for (int i = 0; i < 4; i++){
    int g = tid + i*256;
    int d = g >> 4, c = g & 15, kv = c*4;
    ushort4 o;
    o.x = t[(kv+0)*68 + d];
    o.y = t[(kv+1)*68 + d];
    o.z = t[(kv+2)*68 + d];
    o.w = t[(kv+3)*68 + d];
    *(ushort4*)(Vo + (size_t)(d0+d)*S_ + kv0 + kv) = o;
  }
}

// ---------- main flash-attention kernel ----------
__global__ __launch_bounds__(256, 2)
void attn_fwd(const float* __restrict__ Q, const unsigned short* __restrict__ Kb,
              const unsigned short* __restrict__ Vt, float* __restrict__ Out,
              unsigned short* __restrict__ Opart, float* __restrict__ MLpart,
              int splitFlag){
  __shared__ __attribute__((aligned(16))) unsigned short Klds[2][64*128];
  __shared__ __attribute__((aligned(16))) unsigned short Vlds[2][128*64];
  __shared__ __attribute__((aligned(16))) unsigned short Plds[4][2][16*64];

  const int bi = blockIdx.x;
  const int bh = (bi & 7) + 8*((bi >> 3) & 3);
  const int u  = bi >> 5;
  int qb, mode;
  if (splitFlag){ int c = SPLIT_TAB[u]; qb = c >> 2; mode = c & 3; }
  else { qb = (u < 8) ? (15 - u) : (u - 8); mode = 0; }

  const int tid  = threadIdx.x;
  const int wave = tid >> 6, lane = tid & 63;
  const int ql   = lane & 15, hi = lane >> 4;
  const int wq0  = qb*128 + wave*32;
  const int t0   = (mode == 2) ? qb + 1 : 0;
  const int tEnd = (mode == 1) ? qb + 1 : 2*qb + 2;
  const int dtw  = (mode == 1) ? (1 << 30) : (2*qb + (wave >> 1));
  const float qs = 0.08838834764831845f * 1.44269504088896f; // scale*log2(e), folded into Q

  const char* Kg = (const char*)(Kb + (size_t)bh * S_ * D_);
  const char* Vg = (const char*)(Vt + (size_t)bh * D_ * S_);

  uint32_t koff[4], voff[4];
  #pragma unroll
  for (int i = 0; i < 4; i++){
    int kr = wave*16 + i*4 + (lane >> 4);
    koff[i] = kr*256 + (((lane & 15) ^ ((i & 1)*4 + (lane >> 4))) << 4);
    int vr = wave*32 + i*8 + (lane >> 3);
    voff[i] = vr*(S_*2) + (((lane & 7) ^ (lane >> 3)) << 4);
  }

  auto stage = [&](int nxt, int t){
    const char* kp = Kg + t*16384;
    const char* vp = Vg + t*128;
    char* kd = (char*)&Klds[nxt][0] + wave*4096;
    char* vd = (char*)&Vlds[nxt][0] + wave*4096;
    #pragma unroll
    for (int i = 0; i < 4; i++){
      gld16(kp + koff[i], kd + i*1024);
      gld16(vp + voff[i], vd + i*1024);
    }
  };

  // Q fragments, pre-scaled by qs (B-operand of swapped QK^T)
  uint4 qf[2][4];
  #pragma unroll
  for (int sub = 0; sub < 2; sub++){
    const float* Qp = Q + ((size_t)bh * S_ + (wq0 + sub*16 + ql)) * D_;
    #pragma unroll
    for (int ks = 0; ks < 4; ks++){
      float4 a = *(const float4*)(Qp + ks*32 + hi*8);
      float4 b = *(const float4*)(Qp + ks*32 + hi*8 + 4);
      bf16x8 q8;
      q8[0] = (__bf16)(a.x*qs); q8[1] = (__bf16)(a.y*qs);
      q8[2] = (__bf16)(a.z*qs); q8[3] = (__bf16)(a.w*qs);
      q8[4] = (__bf16)(b.x*qs); q8[5] = (__bf16)(b.y*qs);
      q8[6] = (__bf16)(b.z*qs); q8[7] = (__bf16)(b.w*qs);
      qf[sub][ks] = __builtin_bit_cast(uint4, q8);
    }
  }

  f32x4 o[2][8];
  #pragma unroll
  for (int sub = 0; sub < 2; sub++)
    #pragma unroll
    for (int nb = 0; nb < 8; nb++) o[sub][nb] = (f32x4)(0.f);
  float m_run[2] = {-INFINITY, -INFINITY};
  float l_run[2] = {0.f, 0.f};

  stage(0, t0);
  __syncthreads();

  int cur = 0;
  for (int t = t0; t < tEnd; ++t){
    if (t + 1 < tEnd) stage(cur ^ 1, t + 1);

    if (t <= dtw){
      const int k0 = t*64;
      const bool diag = (t == dtw);
      const char* Kc = (const char*)&Klds[cur][0];
      const char* Vc = (const char*)&Vlds[cur][0];

      f32x4 sa[2][4];
      __builtin_amdgcn_s_setprio(1);
      #pragma unroll
      for (int mb = 0; mb < 4; mb++){
        sa[0][mb] = (f32x4)(0.f);
        sa[1][mb] = (f32x4)(0.f);
        const int row = ql + mb*16;
        #pragma unroll
        for (int ks = 0; ks < 4; ks++){
          int byte = (row*256 + ks*64 + hi*16) ^ ((row & 7) << 4);
          bf16x8 kf = *(const bf16x8*)(Kc + byte);
          sa[0][mb] = __builtin_amdgcn_mfma_f32_16x16x32_bf16(
                        kf, __builtin_bit_cast(bf16x8, qf[0][ks]), sa[0][mb], 0, 0, 0);
          sa[1][mb] = __builtin_amdgcn_mfma_f32_16x16x32_bf16(
                        kf, __builtin_bit_cast(bf16x8, qf[1][ks]), sa[1][mb], 0, 0, 0);
        }
      }
      __builtin_amdgcn_s_setprio(0);

      #pragma unroll
      for (int sub = 0; sub < 2; sub++){
        float p[16];
        float pm = -INFINITY;
        const int q_abs = wq0 + sub*16 + ql;
        #pragma unroll
        for (int mb = 0; mb < 4; mb++){
          #pragma unroll
          for (int r = 0; r < 4; r++){
            float s = sa[sub][mb][r];
            if (diag){
              int kv = k0 + mb*16 + hi*4 + r;
              if (kv > q_abs) s = -1e30f;
            }
            p[mb*4 + r] = s;
            pm = fmaxf(pm, s);
          }
        }
        pm = fmaxf(pm, __shfl_xor(pm, 16));
        pm = fmaxf(pm, __shfl_xor(pm, 32));
        if (__any(pm > m_run[sub] + 11.5f)){
          float mn  = fmaxf(m_run[sub], pm);
          float fac = exp2f(m_run[sub] - mn);
          float f0 = __shfl(fac, hi*4 + 0), f1 = __shfl(fac, hi*4 + 1);
          float f2 = __shfl(fac, hi*4 + 2), f3 = __shfl(fac, hi*4 + 3);
          #pragma unroll
          for (int nb = 0; nb < 8; nb++){
            o[sub][nb][0] *= f0; o[sub][nb][1] *= f1;
            o[sub][nb][2] *= f2; o[sub][nb][3] *= f3;
          }
          l_run[sub] *= fac;
          m_run[sub] = mn;
        }
        float rs = 0.f;
        #pragma unroll
        for (int q2 = 0; q2 < 16; q2++){ p[q2] = exp2f(p[q2] - m_run[sub]); rs += p[q2]; }
        rs += __shfl_xor(rs, 16);
        rs += __shfl_xor(rs, 32);
        l_run[sub] += rs;

        #pragma unroll
        for (int mb = 0; mb < 4; mb++){
          bf16x4 pv;
          pv[0] = (__bf16)p[mb*4+0]; pv[1] = (__bf16)p[mb*4+1];
          pv[2] = (__bf16)p[mb*4+2]; pv[3] = (__bf16)p[mb*4+3];
          int byte = (ql*128 + mb*32 + hi*8) ^ ((ql & 7) << 4);
          *(bf16x4*)((char*)&Plds[wave][sub][0] + byte) = pv;
        }
      }

      __builtin_amdgcn_s_setprio(1);
      #pragma unroll
      for (int ks = 0; ks < 2; ks++){
        int pb = (ql*128 + ks*64 + hi*16) ^ ((ql & 7) << 4);
        bf16x8 pfA = *(const bf16x8*)((const char*)&Plds[wave][0][0] + pb);
        bf16x8 pfB = *(const bf16x8*)((const char*)&Plds[wave][1][0] + pb);
        #pragma unroll
        for (int nb = 0; nb < 8; nb++){
          int d = ql + nb*16;
          int vb = (d*128 + ks*64 + hi*16) ^ ((d & 7) << 4);
          bf16x8 vf = *(const bf16x8*)(Vc + vb);
          o[0][nb] = __builtin_amdgcn_mfma_f32_16x16x32_bf16(pfA, vf, o[0][nb], 0, 0, 0);
          o[1][nb] = __builtin_amdgcn_mfma_f32_16x16x32_bf16(pfB, vf, o[1][nb], 0, 0, 0);
        }
      }
      __builtin_amdgcn_s_setprio(0);
    }

    __syncthreads();
    cur ^= 1;
  }

  if (mode == 0){
    #pragma unroll
    for (int sub = 0; sub < 2; sub++){
      float r0 = 1.f / __shfl(l_run[sub], hi*4 + 0);
      float r1 = 1.f / __shfl(l_run[sub], hi*4 + 1);
      float r2 = 1.f / __shfl(l_run[sub], hi*4 + 2);
      float r3 = 1.f / __shfl(l_run[sub], hi*4 + 3);
      float* Op = Out + ((size_t)bh * S_ + wq0 + sub*16) * D_;
      #pragma unroll
      for (int nb = 0; nb < 8; nb++){
        Op[(size_t)(hi*4 + 0)*D_ + nb*16 + ql] = o[sub][nb][0] * r0;
        Op[(size_t)(hi*4 + 1)*D_ + nb*16 + ql] = o[sub][nb][1] * r1;
        Op[(size_t)(hi*4 + 2)*D_ + nb*16 + ql] = o[sub][nb][2] * r2;
        Op[(size_t)(hi*4 + 3)*D_ + nb*16 + ql] = o[sub][nb][3] * r3;
      }
    }
  } else {
    const int unit = (bh*8 + (qb - 8))*2 + (mode - 1);
    unsigned short* Po = Opart + (size_t)unit * (128*128);
    float* Ml = MLpart + (size_t)unit * 256;
    #pragma unroll
    for (int sub = 0; sub < 2; sub++){
      #pragma unroll
      for (int nb = 0; nb < 8; nb++){
        #pragma unroll
        for (int r = 0; r < 4; r++){
          int row = wave*32 + sub*16 + hi*4 + r;
          __bf16 bv = (__bf16)o[sub][nb][r];
          Po[row*128 + nb*16 + ql] = __builtin_bit_cast(unsigned short, bv);
        }
      }
      if (hi == 0){
        int row = wave*32 + sub*16 + ql;
        Ml[row*2 + 0] = m_run[sub];
        Ml[row*2 + 1] = l_run[sub];
      }
    }
  }
}

// ---------- combine kernel: merge the two kv-chunks of qb>=8 ----------
__global__ __launch_bounds__(256)
void combine(const unsigned short* __restrict__ Opart,
             const float* __restrict__ MLpart, float* __restrict__ Out){
  const int blk = blockIdx.x;           // 0..255 = bh*8 + (qb-8)
  const int bh = blk >> 3, qq = blk & 7;
  const int unit0 = blk * 2;
  const unsigned short* A  = Opart + (size_t)unit0 * (128*128);
  const unsigned short* Bp = A + 128*128;
  const float* MA = MLpart + (size_t)unit0 * 256;
  const float* MB = MA + 256;

  const int row  = threadIdx.x >> 1;
  const int half = threadIdx.x & 1;
  float mA = MA[row*2], lA = MA[row*2 + 1];
  float mB = MB[row*2], lB = MB[row*2 + 1];
  float M  = fmaxf(mA, mB);
  float wA = exp2f(mA - M), wB = exp2f(mB - M);
  float inv = 1.f / (lA*wA + lB*wB);
  wA *= inv; wB *= inv;

  const unsigned short* Ar = A  + row*128 + half*64;
  const unsigned short* Br = Bp + row*128 + half*64;
  float* Or = Out + ((size_t)bh * S_ + (qq + 8)*128 + row) * D_ + half*64;
  #pragma unroll
  for (int c = 0; c < 64; c += 8){
    ushort4 a0 = *(const ushort4*)(Ar + c), a1 = *(const ushort4*)(Ar + c + 4);
    ushort4 b0 = *(const ushort4*)(Br + c), b1 = *(const ushort4*)(Br + c + 4);
    const unsigned short av[8] = {a0.x,a0.y,a0.z,a0.w,a1.x,a1.y,a1.z,a1.w};
    const unsigned short bv[8] = {b0.x,b0.y,b0.z,b0.w,b1.x,b1.y,b1.z,b1.w};
    #pragma unroll
    for (int j = 0; j < 8; j++){
      float fa = __builtin_bit_cast(float, (uint32_t)av[j] << 16);
      float fb = __builtin_bit_cast(float, (uint32_t)bv[j] << 16);
      Or[c + j] = fa*wA + fb*wB;
    }
  }
}

extern "C" void kernel_launch(void* const* d_in, const int* in_sizes, int n_in,
                              void* d_out, int out_size, void* d_ws, size_t ws_size,
                              hipStream_t stream){
  const float* Q = (const float*)d_in[0];
  const float* K = (const float*)d_in[1];
  const float* V = (const float*)d_in[2];
  float* Out = (float*)d_out;

  unsigned short* Kb = (unsigned short*)d_ws;                 // 16.78 MB
  unsigned short* Vt = Kb + (size_t)BH_ * S_ * D_;            // 16.78 MB
  unsigned short* Opart = Vt + (size_t)BH_ * S_ * D_;         // 16.78 MB
  float* MLpart = (float*)(Opart + (size_t)512 * 128 * 128);  // 0.52 MB

  const size_t need = (size_t)BH_*S_*D_*2*3 + (size_t)512*256*4;
  const int split = (ws_size >= need) ? 1 : 0;

  k_cvt<<<2048, 256, 0, stream>>>(K, Kb, BH_*S_*D_/4);
  v_trans<<<dim3(S_/64, D_/64, BH_), 256, 0, stream>>>(V, Vt);
  attn_fwd<<<split ? 768 : 512, 256, 0, stream>>>(Q, Kb, Vt, Out, Opart, MLpart, split);
  if (split) combine<<<256, 256, 0, stream>>>(Opart, MLpart, Out);
}